// Round 15
// baseline (35.910 us; speedup 1.0000x reference)
//
#include <hip/hip_runtime.h>
#include <math.h>

#define BATCH 512
#define SEQL  2048
#define NPTS  (SEQL*3)        // 6144 points per batch
#define NFLT  (NPTS*3)        // 18432 floats per batch per tensor
#define NV    (NFLT/4)        // 4608 float4 per batch per tensor
#define NGRP  (NPTS/4)        // 1536 groups of 4 points
#define TPB   512
#define NWAVE (TPB/64)

// ---------------- mask dtype detection (per-wave, barrier-free) ----------------
// flag: 0 = int32 {0,1}, 1 = uint8 {0,1}, 2 = float32
__device__ __forceinline__ int detect_flag_wave(const void* cm) {
    unsigned int v = ((const unsigned int*)cm)[threadIdx.x & 63];
    bool wi = __all(v <= 1u);
    bool wb = __all((v & 0xFEFEFEFEu) == 0u);
    return wi ? 0 : (wb ? 1 : 2);
}

// ---------------- reduction ----------------
template <int K>
__device__ __forceinline__ void block_reduce(float* acc, float* lds) {
#pragma unroll
    for (int k = 0; k < K; ++k) {
#pragma unroll
        for (int off = 32; off > 0; off >>= 1)
            acc[k] += __shfl_down(acc[k], off, 64);
    }
    int lane = threadIdx.x & 63;
    int wid  = threadIdx.x >> 6;
    if (lane == 0) {
#pragma unroll
        for (int k = 0; k < K; ++k) lds[wid * K + k] = acc[k];
    }
    __syncthreads();
    if (threadIdx.x == 0) {
#pragma unroll
        for (int k = 0; k < K; ++k) {
            float s = 0.f;
#pragma unroll
            for (int w = 0; w < NWAVE; ++w) s += lds[w * K + k];
            acc[k] = s;
        }
    }
}

__device__ __forceinline__ void accum_pt(float* a, float w,
                                         float px, float py, float pz,
                                         float qx, float qy, float qz) {
    a[0] += w;
    float wpx = w * px, wpy = w * py, wpz = w * pz;
    a[1] += wpx; a[2] += wpy; a[3] += wpz;
    a[4] += w * qx; a[5] += w * qy; a[6] += w * qz;
    a[7]  += wpx * qx; a[8]  += wpx * qy; a[9]  += wpx * qz;
    a[10] += wpy * qx; a[11] += wpy * qy; a[12] += wpy * qz;
    a[13] += wpz * qx; a[14] += wpz * qy; a[15] += wpz * qz;
}

// ---------------- closed-form 3x3 Kabsch, all scalars ----------------
// out prm: [0..8]=R, [9..11]=t (R*muP - muQ), [12]=1/d0^2, [13]=cnt
__device__ void kabsch_params(const float* s, float* o) {
    double cnt = (double)s[0];
    double cs = fmax(cnt, 1.0);
    double mup0 = (double)s[1] / cs, mup1 = (double)s[2] / cs, mup2 = (double)s[3] / cs;
    double muq0 = (double)s[4] / cs, muq1 = (double)s[5] / cs, muq2 = (double)s[6] / cs;

    double h00 = (double)s[7]  - cnt * mup0 * muq0;
    double h01 = (double)s[8]  - cnt * mup0 * muq1;
    double h02 = (double)s[9]  - cnt * mup0 * muq2;
    double h10 = (double)s[10] - cnt * mup1 * muq0;
    double h11 = (double)s[11] - cnt * mup1 * muq1;
    double h12 = (double)s[12] - cnt * mup1 * muq2;
    double h20 = (double)s[13] - cnt * mup2 * muq0;
    double h21 = (double)s[14] - cnt * mup2 * muq1;
    double h22 = (double)s[15] - cnt * mup2 * muq2;

    double a00 = h00*h00 + h10*h10 + h20*h20;
    double a01 = h00*h01 + h10*h11 + h20*h21;
    double a02 = h00*h02 + h10*h12 + h20*h22;
    double a11 = h01*h01 + h11*h11 + h21*h21;
    double a12 = h01*h02 + h11*h12 + h21*h22;
    double a22 = h02*h02 + h12*h12 + h22*h22;

    double q3  = (a00 + a11 + a22) / 3.0;
    double pp1 = a01*a01 + a02*a02 + a12*a12;
    double b00 = a00 - q3, b11 = a11 - q3, b22 = a22 - q3;
    double pp2 = b00*b00 + b11*b11 + b22*b22 + 2.0 * pp1;

    double l0, l1, l2;
    double v1x, v1y, v1z, v2x, v2y, v2z, v3x, v3y, v3z;
    if (pp2 <= 1e-24 * (q3 * q3) + 1e-290) {
        l0 = l1 = l2 = q3;
        v1x = 1; v1y = 0; v1z = 0;
        v2x = 0; v2y = 1; v2z = 0;
        v3x = 0; v3y = 0; v3z = 1;
    } else {
        double p = sqrt(pp2 / 6.0), invp = 1.0 / p;
        double c00 = b00*invp, c01 = a01*invp, c02 = a02*invp;
        double c11 = b11*invp, c12 = a12*invp, c22 = b22*invp;
        double detB = c00*(c11*c22 - c12*c12) - c01*(c01*c22 - c12*c02)
                    + c02*(c01*c12 - c11*c02);
        double r = fmin(1.0, fmax(-1.0, detB * 0.5));
        double phi = acos(r) / 3.0;
        l0 = q3 + 2.0 * p * cos(phi);
        l2 = q3 + 2.0 * p * cos(phi + 2.0943951023931953);  // +2pi/3
        l1 = 3.0 * q3 - l0 - l2;

        double aa00 = a00*a00 + a01*a01 + a02*a02;
        double aa01 = a00*a01 + a01*a11 + a02*a12;
        double aa02 = a00*a02 + a01*a12 + a02*a22;
        double aa11 = a01*a01 + a11*a11 + a12*a12;
        double aa12 = a01*a02 + a11*a12 + a12*a22;
        double aa22 = a02*a02 + a12*a12 + a22*a22;

        double s12 = l1 + l2, p12 = l1 * l2;
        double m00 = aa00 - s12*a00 + p12;
        double m01 = aa01 - s12*a01;
        double m02 = aa02 - s12*a02;
        double m11 = aa11 - s12*a11 + p12;
        double m12 = aa12 - s12*a12;
        double m22 = aa22 - s12*a22 + p12;
        double n0 = m00*m00 + m01*m01 + m02*m02;
        double n1 = m01*m01 + m11*m11 + m12*m12;
        double n2 = m02*m02 + m12*m12 + m22*m22;
        bool s0 = (n0 >= n1) && (n0 >= n2);
        bool sA = (n1 >= n2);
        v1x = s0 ? m00 : (sA ? m01 : m02);
        v1y = s0 ? m01 : (sA ? m11 : m12);
        v1z = s0 ? m02 : (sA ? m12 : m22);
        double n1v = sqrt(v1x*v1x + v1y*v1y + v1z*v1z);
        if (n1v > 1e-150) { v1x /= n1v; v1y /= n1v; v1z /= n1v; }
        else { v1x = 1; v1y = 0; v1z = 0; }

        double s01 = l0 + l1, p01 = l0 * l1;
        double t00 = aa00 - s01*a00 + p01;
        double t01 = aa01 - s01*a01;
        double t02 = aa02 - s01*a02;
        double t11 = aa11 - s01*a11 + p01;
        double t12 = aa12 - s01*a12;
        double t22 = aa22 - s01*a22 + p01;
        double u0n = t00*t00 + t01*t01 + t02*t02;
        double u1n = t01*t01 + t11*t11 + t12*t12;
        double u2n = t02*t02 + t12*t12 + t22*t22;
        bool d0c = (u0n >= u1n) && (u0n >= u2n);
        bool dA = (u1n >= u2n);
        v3x = d0c ? t00 : (dA ? t01 : t02);
        v3y = d0c ? t01 : (dA ? t11 : t12);
        v3z = d0c ? t02 : (dA ? t12 : t22);
        double dot13 = v3x*v1x + v3y*v1y + v3z*v1z;
        v3x -= dot13 * v1x; v3y -= dot13 * v1y; v3z -= dot13 * v1z;
        double n3v = sqrt(v3x*v3x + v3y*v3y + v3z*v3z);
        if (n3v > 1e-150) { v3x /= n3v; v3y /= n3v; v3z /= n3v; }
        else {
            double A0 = fabs(v1x), A1 = fabs(v1y), A2 = fabs(v1z);
            double axx = 0, axy = 0, axz = 0;
            if (A0 <= A1 && A0 <= A2) axx = 1; else if (A1 <= A2) axy = 1; else axz = 1;
            double dd = axx*v1x + axy*v1y + axz*v1z;
            v3x = axx - dd*v1x; v3y = axy - dd*v1y; v3z = axz - dd*v1z;
            double nn = sqrt(v3x*v3x + v3y*v3y + v3z*v3z);
            v3x /= nn; v3y /= nn; v3z /= nn;
        }
        v2x = v3y*v1z - v3z*v1y;
        v2y = v3z*v1x - v3x*v1z;
        v2z = v3x*v1y - v3y*v1x;
    }

    double sv0 = sqrt(fmax(l0, 0.0));
    double sv1 = sqrt(fmax(l1, 0.0));
    double sv2 = sqrt(fmax(l2, 0.0));
    double eps = sv0 * 1e-12 + 1e-300;

    double u0x, u0y, u0z, u1x, u1y, u1z, u2x, u2y, u2z;
    {
        double hx = h00*v1x + h01*v1y + h02*v1z;
        double hy = h10*v1x + h11*v1y + h12*v1z;
        double hz = h20*v1x + h21*v1y + h22*v1z;
        if (sv0 > eps) {
            double ix = hx / sv0, iy = hy / sv0, iz = hz / sv0;
            double nn = sqrt(ix*ix + iy*iy + iz*iz);
            if (nn > 1e-300) { ix /= nn; iy /= nn; iz /= nn; }
            u0x = ix; u0y = iy; u0z = iz;
        } else { u0x = 1; u0y = 0; u0z = 0; }
    }
    {
        double hx = h00*v2x + h01*v2y + h02*v2z;
        double hy = h10*v2x + h11*v2y + h12*v2z;
        double hz = h20*v2x + h21*v2y + h22*v2z;
        if (sv1 > eps) {
            double ix = hx / sv1, iy = hy / sv1, iz = hz / sv1;
            double nn = sqrt(ix*ix + iy*iy + iz*iz);
            if (nn > 1e-300) { ix /= nn; iy /= nn; iz /= nn; }
            u1x = ix; u1y = iy; u1z = iz;
        } else {
            double A0 = fabs(u0x), A1 = fabs(u0y), A2 = fabs(u0z);
            double axx = 0, axy = 0, axz = 0;
            if (A0 <= A1 && A0 <= A2) axx = 1; else if (A1 <= A2) axy = 1; else axz = 1;
            double cx = u0y*axz - u0z*axy;
            double cy = u0z*axx - u0x*axz;
            double cz = u0x*axy - u0y*axx;
            double nn = sqrt(cx*cx + cy*cy + cz*cz);
            if (nn > 1e-300) { cx /= nn; cy /= nn; cz /= nn; }
            u1x = cx; u1y = cy; u1z = cz;
        }
    }
    {
        double hx = h00*v3x + h01*v3y + h02*v3z;
        double hy = h10*v3x + h11*v3y + h12*v3z;
        double hz = h20*v3x + h21*v3y + h22*v3z;
        if (sv2 > eps) {
            double ix = hx / sv2, iy = hy / sv2, iz = hz / sv2;
            double nn = sqrt(ix*ix + iy*iy + iz*iz);
            if (nn > 1e-300) { ix /= nn; iy /= nn; iz /= nn; }
            u2x = ix; u2y = iy; u2z = iz;
        } else {
            u2x = u0y*u1z - u0z*u1y;
            u2y = u0z*u1x - u0x*u1z;
            u2z = u0x*u1y - u0y*u1x;
            double nn = sqrt(u2x*u2x + u2y*u2y + u2z*u2z);
            if (nn > 1e-300) { u2x /= nn; u2y /= nn; u2z /= nn; }
        }
    }

    double detH = h00*(h11*h22 - h12*h21) - h01*(h10*h22 - h12*h20)
                + h02*(h10*h21 - h11*h20);
    double e2 = (detH > 0.0) ? 1.0 : ((detH < 0.0) ? -1.0 : 0.0);

    double R00 = v1x*u0x + v2x*u1x + e2*v3x*u2x;
    double R01 = v1x*u0y + v2x*u1y + e2*v3x*u2y;
    double R02 = v1x*u0z + v2x*u1z + e2*v3x*u2z;
    double R10 = v1y*u0x + v2y*u1x + e2*v3y*u2x;
    double R11 = v1y*u0y + v2y*u1y + e2*v3y*u2y;
    double R12 = v1y*u0z + v2y*u1z + e2*v3y*u2z;
    double R20 = v1z*u0x + v2z*u1x + e2*v3z*u2x;
    double R21 = v1z*u0y + v2z*u1y + e2*v3z*u2y;
    double R22 = v1z*u0z + v2z*u1z + e2*v3z*u2z;

    o[0] = (float)R00; o[1] = (float)R01; o[2] = (float)R02;
    o[3] = (float)R10; o[4] = (float)R11; o[5] = (float)R12;
    o[6] = (float)R20; o[7] = (float)R21; o[8] = (float)R22;

    o[9]  = (float)(R00*mup0 + R01*mup1 + R02*mup2 - muq0);
    o[10] = (float)(R10*mup0 + R11*mup1 + R12*mup2 - muq1);
    o[11] = (float)(R20*mup0 + R21*mup1 + R22*mup2 - muq2);

    double n = (double)s[16];
    double d0 = 1.24 * cbrt(fmax(n - 15.0, 1e-3)) - 1.8;
    d0 = fmax(d0, 1e-3);
    o[12] = (float)(1.0 / (d0 * d0));
    o[13] = (float)cnt;
}

// ---------------- fused kernel: coalesced loads + LDS bounce transpose ------
// Every global_load_dwordx4 has lane-stride 16B (coalesced: 16 lines/instr,
// vs the previous 48B point-triplet stride = 48 lines/instr -> ~1/3 rate).
// LDS sT[4608] (73.7 KB f32) transposes linear float4s -> per-thread point
// triplets; reused serially for P then Q. Phase C is pure-register.
__global__ __launch_bounds__(TPB, 2) void k_fused(
    const float* __restrict__ P, const float* __restrict__ Q,
    const void* __restrict__ cmask, const void* __restrict__ rmask,
    float* __restrict__ out) {
    int b = blockIdx.x;
    int tid = threadIdx.x;
    __shared__ float4 sT[NV];          // 73.7 KB bounce buffer
    __shared__ float lds[NWAVE * 17];
    __shared__ float prm[14];
    int flag = detect_flag_wave(cmask);

    const float4* Pv = (const float4*)(P + (size_t)b * NFLT);
    const float4* Qv = (const float4*)(Q + (size_t)b * NFLT);
    size_t gbase = (size_t)b * NGRP;

    // ---- masks (already coalesced: 16B or 4B lane stride) ----
    float w[12];
    float rescnt;
    {
        size_t rg = (size_t)b * (SEQL / 4) + tid;
        if (flag == 0) {
            const int4* cm4 = (const int4*)cmask;
            int4 m0 = cm4[gbase + tid], m1 = cm4[gbase + tid + TPB], m2 = cm4[gbase + tid + 2*TPB];
            int4 rv = ((const int4*)rmask)[rg];
            w[0]=m0.x?1.f:0.f; w[1]=m0.y?1.f:0.f; w[2]=m0.z?1.f:0.f; w[3]=m0.w?1.f:0.f;
            w[4]=m1.x?1.f:0.f; w[5]=m1.y?1.f:0.f; w[6]=m1.z?1.f:0.f; w[7]=m1.w?1.f:0.f;
            w[8]=m2.x?1.f:0.f; w[9]=m2.y?1.f:0.f; w[10]=m2.z?1.f:0.f; w[11]=m2.w?1.f:0.f;
            rescnt = (rv.x?1.f:0.f) + (rv.y?1.f:0.f) + (rv.z?1.f:0.f) + (rv.w?1.f:0.f);
        } else if (flag == 1) {
            const unsigned int* cmw = (const unsigned int*)cmask;
            unsigned int m0 = cmw[gbase + tid], m1 = cmw[gbase + tid + TPB], m2 = cmw[gbase + tid + 2*TPB];
            unsigned int rv = ((const unsigned int*)rmask)[rg];
            w[0]=(m0&0xFFu)?1.f:0.f; w[1]=(m0&0xFF00u)?1.f:0.f; w[2]=(m0&0xFF0000u)?1.f:0.f; w[3]=(m0&0xFF000000u)?1.f:0.f;
            w[4]=(m1&0xFFu)?1.f:0.f; w[5]=(m1&0xFF00u)?1.f:0.f; w[6]=(m1&0xFF0000u)?1.f:0.f; w[7]=(m1&0xFF000000u)?1.f:0.f;
            w[8]=(m2&0xFFu)?1.f:0.f; w[9]=(m2&0xFF00u)?1.f:0.f; w[10]=(m2&0xFF0000u)?1.f:0.f; w[11]=(m2&0xFF000000u)?1.f:0.f;
            rescnt = (float)__popc(rv);
        } else {
            const float4* cmf = (const float4*)cmask;
            float4 m0 = cmf[gbase + tid], m1 = cmf[gbase + tid + TPB], m2 = cmf[gbase + tid + 2*TPB];
            float4 rv = ((const float4*)rmask)[rg];
            w[0]=m0.x!=0.f?1.f:0.f; w[1]=m0.y!=0.f?1.f:0.f; w[2]=m0.z!=0.f?1.f:0.f; w[3]=m0.w!=0.f?1.f:0.f;
            w[4]=m1.x!=0.f?1.f:0.f; w[5]=m1.y!=0.f?1.f:0.f; w[6]=m1.z!=0.f?1.f:0.f; w[7]=m1.w!=0.f?1.f:0.f;
            w[8]=m2.x!=0.f?1.f:0.f; w[9]=m2.y!=0.f?1.f:0.f; w[10]=m2.z!=0.f?1.f:0.f; w[11]=m2.w!=0.f?1.f:0.f;
            rescnt = (rv.x!=0.f?1.f:0.f) + (rv.y!=0.f?1.f:0.f) + (rv.z!=0.f?1.f:0.f) + (rv.w!=0.f?1.f:0.f);
        }
    }

    // ---- P: coalesced global -> LDS -> per-thread point triplets ----
    float4 t[9];
#pragma unroll
    for (int k = 0; k < 9; ++k) t[k] = Pv[tid + k * TPB];
#pragma unroll
    for (int k = 0; k < 9; ++k) sT[tid + k * TPB] = t[k];
    __syncthreads();
    float4 p[9];
#pragma unroll
    for (int k = 0; k < 3; ++k) {
        int g3 = 3 * (tid + k * TPB);
        p[3*k+0] = sT[g3 + 0]; p[3*k+1] = sT[g3 + 1]; p[3*k+2] = sT[g3 + 2];
    }
    __syncthreads();   // all P-triplet reads done before overwrite

    // ---- Q: coalesced global -> LDS -> triplets ----
#pragma unroll
    for (int k = 0; k < 9; ++k) t[k] = Qv[tid + k * TPB];
#pragma unroll
    for (int k = 0; k < 9; ++k) sT[tid + k * TPB] = t[k];
    __syncthreads();
    float4 q[9];
#pragma unroll
    for (int k = 0; k < 3; ++k) {
        int g3 = 3 * (tid + k * TPB);
        q[3*k+0] = sT[g3 + 0]; q[3*k+1] = sT[g3 + 1]; q[3*k+2] = sT[g3 + 2];
    }

    // ---- phase A: masked sums (exact f32, from registers) ----
    float acc[17];
#pragma unroll
    for (int k = 0; k < 17; ++k) acc[k] = 0.0f;
    acc[16] = rescnt;

#pragma unroll
    for (int k = 0; k < 3; ++k) {
        float4 p0 = p[3*k+0], p1 = p[3*k+1], p2 = p[3*k+2];
        float4 q0 = q[3*k+0], q1 = q[3*k+1], q2 = q[3*k+2];
        accum_pt(acc, w[4*k+0], p0.x, p0.y, p0.z, q0.x, q0.y, q0.z);
        accum_pt(acc, w[4*k+1], p0.w, p1.x, p1.y, q0.w, q1.x, q1.y);
        accum_pt(acc, w[4*k+2], p1.z, p1.w, p2.x, q1.z, q1.w, q2.x);
        accum_pt(acc, w[4*k+3], p2.y, p2.z, p2.w, q2.y, q2.z, q2.w);
    }

    block_reduce<17>(acc, lds);

    // ---- phase B: thread 0, scratch-free closed-form Kabsch ----
    if (tid == 0) kabsch_params(acc, prm);
    __syncthreads();

    float R0 = prm[0], R1 = prm[1], R2 = prm[2];
    float R3 = prm[3], R4 = prm[4], R5 = prm[5];
    float R6 = prm[6], R7 = prm[7], R8 = prm[8];
    float tx = prm[9], ty = prm[10], tz = prm[11];
    float inv = prm[12], cnt = prm[13];

    // ---- phase C: rotate + TM, pure registers ----
    float acc2 = 0.0f;
#pragma unroll
    for (int k = 0; k < 3; ++k) {
        float4 p0 = p[3*k+0], p1 = p[3*k+1], p2 = p[3*k+2];
        float4 q0 = q[3*k+0], q1 = q[3*k+1], q2 = q[3*k+2];
        float px[4] = {p0.x, p0.w, p1.z, p2.y};
        float py[4] = {p0.y, p1.x, p1.w, p2.z};
        float pz[4] = {p0.z, p1.y, p2.x, p2.w};
        float qx[4] = {q0.x, q0.w, q1.z, q2.y};
        float qy[4] = {q0.y, q1.x, q1.w, q2.z};
        float qz[4] = {q0.z, q1.y, q2.x, q2.w};
#pragma unroll
        for (int u = 0; u < 4; ++u) {
            float dx = R0*px[u] + R1*py[u] + R2*pz[u] - tx - qx[u];
            float dy = R3*px[u] + R4*py[u] + R5*pz[u] - ty - qy[u];
            float dz = R6*px[u] + R7*py[u] + R8*pz[u] - tz - qz[u];
            float d2 = dx*dx + dy*dy + dz*dz;
            acc2 += w[4*k+u] / (1.0f + d2 * inv);
        }
    }
    float a2[1] = {acc2};
    block_reduce<1>(a2, lds);
    if (tid == 0)
        out[b] = (cnt > 0.0f) ? a2[0] / fmaxf(cnt, 1.0f) : 0.0f;
}

// ---------------- launcher ----------------
extern "C" void kernel_launch(void* const* d_in, const int* in_sizes, int n_in,
                              void* d_out, int out_size, void* d_ws, size_t ws_size,
                              hipStream_t stream) {
    const float* P = (const float*)d_in[0];
    const float* Q = (const float*)d_in[1];
    const void* cm = d_in[2];
    const void* rm = d_in[3];
    float* out = (float*)d_out;

    k_fused<<<BATCH, TPB, 0, stream>>>(P, Q, cm, rm, out);
}

// Round 16
// 34.117 us; speedup vs baseline: 1.0525x; 1.0525x over previous
//
#include <hip/hip_runtime.h>
#include <hip/hip_fp16.h>
#include <math.h>

#define BATCH 512
#define SEQL  2048
#define NPTS  (SEQL*3)        // 6144 points per batch
#define NFLT  (NPTS*3)        // 18432 floats per batch per tensor
#define NGRP  (NPTS/4)        // 1536 groups of 4 points
#define TPB   768             // 12 waves; 2 blocks/CU => ALL 512 blocks resident
#define NWAVE (TPB/64)

// ---------------- fp16 pack/unpack for the LDS stash ----------------
__device__ __forceinline__ uint2 pack4(float4 v) {
    __half2 lo = __floats2half2_rn(v.x, v.y);
    __half2 hi = __floats2half2_rn(v.z, v.w);
    uint2 r;
    r.x = *(unsigned int*)&lo;
    r.y = *(unsigned int*)&hi;
    return r;
}
__device__ __forceinline__ float4 unpack4(uint2 u) {
    __half2 lo = *(__half2*)&u.x;
    __half2 hi = *(__half2*)&u.y;
    float2 a = __half22float2(lo);
    float2 b = __half22float2(hi);
    return make_float4(a.x, a.y, b.x, b.y);
}

// ---------------- mask dtype detection (per-wave, barrier-free) ----------------
// flag: 0 = int32 {0,1}, 1 = uint8 {0,1}, 2 = float32
__device__ __forceinline__ int detect_flag_wave(const void* cm) {
    unsigned int v = ((const unsigned int*)cm)[threadIdx.x & 63];
    bool wi = __all(v <= 1u);
    bool wb = __all((v & 0xFEFEFEFEu) == 0u);
    return wi ? 0 : (wb ? 1 : 2);
}

// ---------------- reduction ----------------
template <int K>
__device__ __forceinline__ void block_reduce(float* acc, float* lds) {
#pragma unroll
    for (int k = 0; k < K; ++k) {
#pragma unroll
        for (int off = 32; off > 0; off >>= 1)
            acc[k] += __shfl_down(acc[k], off, 64);
    }
    int lane = threadIdx.x & 63;
    int wid  = threadIdx.x >> 6;
    if (lane == 0) {
#pragma unroll
        for (int k = 0; k < K; ++k) lds[wid * K + k] = acc[k];
    }
    __syncthreads();
    if (threadIdx.x == 0) {
#pragma unroll
        for (int k = 0; k < K; ++k) {
            float s = 0.f;
#pragma unroll
            for (int w = 0; w < NWAVE; ++w) s += lds[w * K + k];
            acc[k] = s;
        }
    }
}

__device__ __forceinline__ void accum_pt(float* a, float w,
                                         float px, float py, float pz,
                                         float qx, float qy, float qz) {
    a[0] += w;
    float wpx = w * px, wpy = w * py, wpz = w * pz;
    a[1] += wpx; a[2] += wpy; a[3] += wpz;
    a[4] += w * qx; a[5] += w * qy; a[6] += w * qz;
    a[7]  += wpx * qx; a[8]  += wpx * qy; a[9]  += wpx * qz;
    a[10] += wpy * qx; a[11] += wpy * qy; a[12] += wpy * qz;
    a[13] += wpz * qx; a[14] += wpz * qy; a[15] += wpz * qz;
}

// ---------------- closed-form 3x3 Kabsch, all scalars ----------------
// out prm: [0..8]=R, [9..11]=t (R*muP - muQ), [12]=1/d0^2, [13]=cnt
__device__ void kabsch_params(const float* s, float* o) {
    double cnt = (double)s[0];
    double cs = fmax(cnt, 1.0);
    double mup0 = (double)s[1] / cs, mup1 = (double)s[2] / cs, mup2 = (double)s[3] / cs;
    double muq0 = (double)s[4] / cs, muq1 = (double)s[5] / cs, muq2 = (double)s[6] / cs;

    double h00 = (double)s[7]  - cnt * mup0 * muq0;
    double h01 = (double)s[8]  - cnt * mup0 * muq1;
    double h02 = (double)s[9]  - cnt * mup0 * muq2;
    double h10 = (double)s[10] - cnt * mup1 * muq0;
    double h11 = (double)s[11] - cnt * mup1 * muq1;
    double h12 = (double)s[12] - cnt * mup1 * muq2;
    double h20 = (double)s[13] - cnt * mup2 * muq0;
    double h21 = (double)s[14] - cnt * mup2 * muq1;
    double h22 = (double)s[15] - cnt * mup2 * muq2;

    double a00 = h00*h00 + h10*h10 + h20*h20;
    double a01 = h00*h01 + h10*h11 + h20*h21;
    double a02 = h00*h02 + h10*h12 + h20*h22;
    double a11 = h01*h01 + h11*h11 + h21*h21;
    double a12 = h01*h02 + h11*h12 + h21*h22;
    double a22 = h02*h02 + h12*h12 + h22*h22;

    double q3  = (a00 + a11 + a22) / 3.0;
    double pp1 = a01*a01 + a02*a02 + a12*a12;
    double b00 = a00 - q3, b11 = a11 - q3, b22 = a22 - q3;
    double pp2 = b00*b00 + b11*b11 + b22*b22 + 2.0 * pp1;

    double l0, l1, l2;
    double v1x, v1y, v1z, v2x, v2y, v2z, v3x, v3y, v3z;
    if (pp2 <= 1e-24 * (q3 * q3) + 1e-290) {
        l0 = l1 = l2 = q3;
        v1x = 1; v1y = 0; v1z = 0;
        v2x = 0; v2y = 1; v2z = 0;
        v3x = 0; v3y = 0; v3z = 1;
    } else {
        double p = sqrt(pp2 / 6.0), invp = 1.0 / p;
        double c00 = b00*invp, c01 = a01*invp, c02 = a02*invp;
        double c11 = b11*invp, c12 = a12*invp, c22 = b22*invp;
        double detB = c00*(c11*c22 - c12*c12) - c01*(c01*c22 - c12*c02)
                    + c02*(c01*c12 - c11*c02);
        double r = fmin(1.0, fmax(-1.0, detB * 0.5));
        double phi = acos(r) / 3.0;
        l0 = q3 + 2.0 * p * cos(phi);
        l2 = q3 + 2.0 * p * cos(phi + 2.0943951023931953);  // +2pi/3
        l1 = 3.0 * q3 - l0 - l2;

        double aa00 = a00*a00 + a01*a01 + a02*a02;
        double aa01 = a00*a01 + a01*a11 + a02*a12;
        double aa02 = a00*a02 + a01*a12 + a02*a22;
        double aa11 = a01*a01 + a11*a11 + a12*a12;
        double aa12 = a01*a02 + a11*a12 + a12*a22;
        double aa22 = a02*a02 + a12*a12 + a22*a22;

        double s12 = l1 + l2, p12 = l1 * l2;
        double m00 = aa00 - s12*a00 + p12;
        double m01 = aa01 - s12*a01;
        double m02 = aa02 - s12*a02;
        double m11 = aa11 - s12*a11 + p12;
        double m12 = aa12 - s12*a12;
        double m22 = aa22 - s12*a22 + p12;
        double n0 = m00*m00 + m01*m01 + m02*m02;
        double n1 = m01*m01 + m11*m11 + m12*m12;
        double n2 = m02*m02 + m12*m12 + m22*m22;
        bool s0 = (n0 >= n1) && (n0 >= n2);
        bool sA = (n1 >= n2);
        v1x = s0 ? m00 : (sA ? m01 : m02);
        v1y = s0 ? m01 : (sA ? m11 : m12);
        v1z = s0 ? m02 : (sA ? m12 : m22);
        double n1v = sqrt(v1x*v1x + v1y*v1y + v1z*v1z);
        if (n1v > 1e-150) { v1x /= n1v; v1y /= n1v; v1z /= n1v; }
        else { v1x = 1; v1y = 0; v1z = 0; }

        double s01 = l0 + l1, p01 = l0 * l1;
        double t00 = aa00 - s01*a00 + p01;
        double t01 = aa01 - s01*a01;
        double t02 = aa02 - s01*a02;
        double t11 = aa11 - s01*a11 + p01;
        double t12 = aa12 - s01*a12;
        double t22 = aa22 - s01*a22 + p01;
        double u0n = t00*t00 + t01*t01 + t02*t02;
        double u1n = t01*t01 + t11*t11 + t12*t12;
        double u2n = t02*t02 + t12*t12 + t22*t22;
        bool d0c = (u0n >= u1n) && (u0n >= u2n);
        bool dA = (u1n >= u2n);
        v3x = d0c ? t00 : (dA ? t01 : t02);
        v3y = d0c ? t01 : (dA ? t11 : t12);
        v3z = d0c ? t02 : (dA ? t12 : t22);
        double dot13 = v3x*v1x + v3y*v1y + v3z*v1z;
        v3x -= dot13 * v1x; v3y -= dot13 * v1y; v3z -= dot13 * v1z;
        double n3v = sqrt(v3x*v3x + v3y*v3y + v3z*v3z);
        if (n3v > 1e-150) { v3x /= n3v; v3y /= n3v; v3z /= n3v; }
        else {
            double A0 = fabs(v1x), A1 = fabs(v1y), A2 = fabs(v1z);
            double axx = 0, axy = 0, axz = 0;
            if (A0 <= A1 && A0 <= A2) axx = 1; else if (A1 <= A2) axy = 1; else axz = 1;
            double dd = axx*v1x + axy*v1y + axz*v1z;
            v3x = axx - dd*v1x; v3y = axy - dd*v1y; v3z = axz - dd*v1z;
            double nn = sqrt(v3x*v3x + v3y*v3y + v3z*v3z);
            v3x /= nn; v3y /= nn; v3z /= nn;
        }
        v2x = v3y*v1z - v3z*v1y;
        v2y = v3z*v1x - v3x*v1z;
        v2z = v3x*v1y - v3y*v1x;
    }

    double sv0 = sqrt(fmax(l0, 0.0));
    double sv1 = sqrt(fmax(l1, 0.0));
    double sv2 = sqrt(fmax(l2, 0.0));
    double eps = sv0 * 1e-12 + 1e-300;

    double u0x, u0y, u0z, u1x, u1y, u1z, u2x, u2y, u2z;
    {
        double hx = h00*v1x + h01*v1y + h02*v1z;
        double hy = h10*v1x + h11*v1y + h12*v1z;
        double hz = h20*v1x + h21*v1y + h22*v1z;
        if (sv0 > eps) {
            double ix = hx / sv0, iy = hy / sv0, iz = hz / sv0;
            double nn = sqrt(ix*ix + iy*iy + iz*iz);
            if (nn > 1e-300) { ix /= nn; iy /= nn; iz /= nn; }
            u0x = ix; u0y = iy; u0z = iz;
        } else { u0x = 1; u0y = 0; u0z = 0; }
    }
    {
        double hx = h00*v2x + h01*v2y + h02*v2z;
        double hy = h10*v2x + h11*v2y + h12*v2z;
        double hz = h20*v2x + h21*v2y + h22*v2z;
        if (sv1 > eps) {
            double ix = hx / sv1, iy = hy / sv1, iz = hz / sv1;
            double nn = sqrt(ix*ix + iy*iy + iz*iz);
            if (nn > 1e-300) { ix /= nn; iy /= nn; iz /= nn; }
            u1x = ix; u1y = iy; u1z = iz;
        } else {
            double A0 = fabs(u0x), A1 = fabs(u0y), A2 = fabs(u0z);
            double axx = 0, axy = 0, axz = 0;
            if (A0 <= A1 && A0 <= A2) axx = 1; else if (A1 <= A2) axy = 1; else axz = 1;
            double cx = u0y*axz - u0z*axy;
            double cy = u0z*axx - u0x*axz;
            double cz = u0x*axy - u0y*axx;
            double nn = sqrt(cx*cx + cy*cy + cz*cz);
            if (nn > 1e-300) { cx /= nn; cy /= nn; cz /= nn; }
            u1x = cx; u1y = cy; u1z = cz;
        }
    }
    {
        double hx = h00*v3x + h01*v3y + h02*v3z;
        double hy = h10*v3x + h11*v3y + h12*v3z;
        double hz = h20*v3x + h21*v3y + h22*v3z;
        if (sv2 > eps) {
            double ix = hx / sv2, iy = hy / sv2, iz = hz / sv2;
            double nn = sqrt(ix*ix + iy*iy + iz*iz);
            if (nn > 1e-300) { ix /= nn; iy /= nn; iz /= nn; }
            u2x = ix; u2y = iy; u2z = iz;
        } else {
            u2x = u0y*u1z - u0z*u1y;
            u2y = u0z*u1x - u0x*u1z;
            u2z = u0x*u1y - u0y*u1x;
            double nn = sqrt(u2x*u2x + u2y*u2y + u2z*u2z);
            if (nn > 1e-300) { u2x /= nn; u2y /= nn; u2z /= nn; }
        }
    }

    double detH = h00*(h11*h22 - h12*h21) - h01*(h10*h22 - h12*h20)
                + h02*(h10*h21 - h11*h20);
    double e2 = (detH > 0.0) ? 1.0 : ((detH < 0.0) ? -1.0 : 0.0);

    double R00 = v1x*u0x + v2x*u1x + e2*v3x*u2x;
    double R01 = v1x*u0y + v2x*u1y + e2*v3x*u2y;
    double R02 = v1x*u0z + v2x*u1z + e2*v3x*u2z;
    double R10 = v1y*u0x + v2y*u1x + e2*v3y*u2x;
    double R11 = v1y*u0y + v2y*u1y + e2*v3y*u2y;
    double R12 = v1y*u0z + v2y*u1z + e2*v3y*u2z;
    double R20 = v1z*u0x + v2z*u1x + e2*v3z*u2x;
    double R21 = v1z*u0y + v2z*u1y + e2*v3z*u2y;
    double R22 = v1z*u0z + v2z*u1z + e2*v3z*u2z;

    o[0] = (float)R00; o[1] = (float)R01; o[2] = (float)R02;
    o[3] = (float)R10; o[4] = (float)R11; o[5] = (float)R12;
    o[6] = (float)R20; o[7] = (float)R21; o[8] = (float)R22;

    o[9]  = (float)(R00*mup0 + R01*mup1 + R02*mup2 - muq0);
    o[10] = (float)(R10*mup0 + R11*mup1 + R12*mup2 - muq1);
    o[11] = (float)(R20*mup0 + R21*mup1 + R22*mup2 - muq2);

    double n = (double)s[16];
    double d0 = 1.24 * cbrt(fmax(n - 15.0, 1e-3)) - 1.8;
    d0 = fmax(d0, 1e-3);
    o[12] = (float)(1.0 / (d0 * d0));
    o[13] = (float)cnt;
}

// ---------------- fused kernel ----------------
// TPB=768 (12 waves), LDS 74.6 KB -> 2 blocks/CU -> ALL 512 blocks resident
// in ONE round (R11 ran 2 sequential rounds at 16 waves/CU). (768,6) caps
// VGPR at ~85; this code naturally compiles to 64 (R11-R14, no spill).
__global__ __launch_bounds__(TPB, 6) void k_fused(
    const float* __restrict__ P, const float* __restrict__ Q,
    const void* __restrict__ cmask, const void* __restrict__ rmask,
    float* __restrict__ out) {
    int b = blockIdx.x;
    int tid = threadIdx.x;
    __shared__ float lds[NWAVE * 17];
    __shared__ float prm[14];
    // fp16 stash of ALL 1536 groups: 6 x 1536 x 8B = 73.7 KB
    __shared__ uint2 sP0[NGRP], sP1[NGRP], sP2[NGRP];
    __shared__ uint2 sQ0[NGRP], sQ1[NGRP], sQ2[NGRP];
    int flag = detect_flag_wave(cmask);   // per-wave, no barrier

    const float4* Pv = (const float4*)(P + (size_t)b * NFLT);
    const float4* Qv = (const float4*)(Q + (size_t)b * NFLT);
    size_t gbase = (size_t)b * NGRP;

    // ---- phase A: loads (2 groups = 8 points per thread) ----
    float4 p[6], q[6];
#pragma unroll
    for (int k = 0; k < 2; ++k) {
        int g = tid + k * TPB;
        p[3*k+0] = Pv[3*g+0]; p[3*k+1] = Pv[3*g+1]; p[3*k+2] = Pv[3*g+2];
        q[3*k+0] = Qv[3*g+0]; q[3*k+1] = Qv[3*g+1]; q[3*k+2] = Qv[3*g+2];
    }
    float w[8];
    float rescnt = 0.f;
    {
        if (flag == 0) {
            const int4* cm4 = (const int4*)cmask;
            int4 m0 = cm4[gbase + tid], m1 = cm4[gbase + tid + TPB];
            w[0]=m0.x?1.f:0.f; w[1]=m0.y?1.f:0.f; w[2]=m0.z?1.f:0.f; w[3]=m0.w?1.f:0.f;
            w[4]=m1.x?1.f:0.f; w[5]=m1.y?1.f:0.f; w[6]=m1.z?1.f:0.f; w[7]=m1.w?1.f:0.f;
            if (tid < SEQL/4) {
                int4 rv = ((const int4*)rmask)[(size_t)b * (SEQL/4) + tid];
                rescnt = (rv.x?1.f:0.f) + (rv.y?1.f:0.f) + (rv.z?1.f:0.f) + (rv.w?1.f:0.f);
            }
        } else if (flag == 1) {
            const unsigned int* cmw = (const unsigned int*)cmask;
            unsigned int m0 = cmw[gbase + tid], m1 = cmw[gbase + tid + TPB];
            w[0]=(m0&0xFFu)?1.f:0.f; w[1]=(m0&0xFF00u)?1.f:0.f; w[2]=(m0&0xFF0000u)?1.f:0.f; w[3]=(m0&0xFF000000u)?1.f:0.f;
            w[4]=(m1&0xFFu)?1.f:0.f; w[5]=(m1&0xFF00u)?1.f:0.f; w[6]=(m1&0xFF0000u)?1.f:0.f; w[7]=(m1&0xFF000000u)?1.f:0.f;
            if (tid < SEQL/4) {
                unsigned int rv = ((const unsigned int*)rmask)[(size_t)b * (SEQL/4) + tid];
                rescnt = (float)__popc(rv);
            }
        } else {
            const float4* cmf = (const float4*)cmask;
            float4 m0 = cmf[gbase + tid], m1 = cmf[gbase + tid + TPB];
            w[0]=m0.x!=0.f?1.f:0.f; w[1]=m0.y!=0.f?1.f:0.f; w[2]=m0.z!=0.f?1.f:0.f; w[3]=m0.w!=0.f?1.f:0.f;
            w[4]=m1.x!=0.f?1.f:0.f; w[5]=m1.y!=0.f?1.f:0.f; w[6]=m1.z!=0.f?1.f:0.f; w[7]=m1.w!=0.f?1.f:0.f;
            if (tid < SEQL/4) {
                float4 rv = ((const float4*)rmask)[(size_t)b * (SEQL/4) + tid];
                rescnt = (rv.x!=0.f?1.f:0.f) + (rv.y!=0.f?1.f:0.f)
                       + (rv.z!=0.f?1.f:0.f) + (rv.w!=0.f?1.f:0.f);
            }
        }
    }

    // stash ALL groups as fp16
#pragma unroll
    for (int k = 0; k < 2; ++k) {
        int g = tid + k * TPB;
        sP0[g] = pack4(p[3*k+0]); sP1[g] = pack4(p[3*k+1]); sP2[g] = pack4(p[3*k+2]);
        sQ0[g] = pack4(q[3*k+0]); sQ1[g] = pack4(q[3*k+1]); sQ2[g] = pack4(q[3*k+2]);
    }

    float acc[17];
#pragma unroll
    for (int k = 0; k < 17; ++k) acc[k] = 0.0f;
    acc[16] = rescnt;

#pragma unroll
    for (int k = 0; k < 2; ++k) {
        float4 p0 = p[3*k+0], p1 = p[3*k+1], p2 = p[3*k+2];
        float4 q0 = q[3*k+0], q1 = q[3*k+1], q2 = q[3*k+2];
        accum_pt(acc, w[4*k+0], p0.x, p0.y, p0.z, q0.x, q0.y, q0.z);
        accum_pt(acc, w[4*k+1], p0.w, p1.x, p1.y, q0.w, q1.x, q1.y);
        accum_pt(acc, w[4*k+2], p1.z, p1.w, p2.x, q1.z, q1.w, q2.x);
        accum_pt(acc, w[4*k+3], p2.y, p2.z, p2.w, q2.y, q2.z, q2.w);
    }

    block_reduce<17>(acc, lds);

    // ---- phase B: thread 0, scratch-free closed-form Kabsch ----
    if (tid == 0) kabsch_params(acc, prm);
    __syncthreads();

    float R0 = prm[0], R1 = prm[1], R2 = prm[2];
    float R3 = prm[3], R4 = prm[4], R5 = prm[5];
    float R6 = prm[6], R7 = prm[7], R8 = prm[8];
    float tx = prm[9], ty = prm[10], tz = prm[11];
    float inv = prm[12], cnt = prm[13];

    // ---- phase C: rotate + TM, entirely from the fp16 LDS stash ----
    float acc2 = 0.0f;
#pragma unroll
    for (int k = 0; k < 2; ++k) {
        int g = tid + k * TPB;
        float4 p0 = unpack4(sP0[g]), p1 = unpack4(sP1[g]), p2 = unpack4(sP2[g]);
        float4 q0 = unpack4(sQ0[g]), q1 = unpack4(sQ1[g]), q2 = unpack4(sQ2[g]);
        float px[4] = {p0.x, p0.w, p1.z, p2.y};
        float py[4] = {p0.y, p1.x, p1.w, p2.z};
        float pz[4] = {p0.z, p1.y, p2.x, p2.w};
        float qx[4] = {q0.x, q0.w, q1.z, q2.y};
        float qy[4] = {q0.y, q1.x, q1.w, q2.z};
        float qz[4] = {q0.z, q1.y, q2.x, q2.w};
#pragma unroll
        for (int u = 0; u < 4; ++u) {
            float dx = R0*px[u] + R1*py[u] + R2*pz[u] - tx - qx[u];
            float dy = R3*px[u] + R4*py[u] + R5*pz[u] - ty - qy[u];
            float dz = R6*px[u] + R7*py[u] + R8*pz[u] - tz - qz[u];
            float d2 = dx*dx + dy*dy + dz*dz;
            acc2 += w[4*k+u] / (1.0f + d2 * inv);
        }
    }
    __syncthreads();   // lds reuse barrier
    float a2[1] = {acc2};
    block_reduce<1>(a2, lds);
    if (tid == 0)
        out[b] = (cnt > 0.0f) ? a2[0] / fmaxf(cnt, 1.0f) : 0.0f;
}

// ---------------- launcher ----------------
extern "C" void kernel_launch(void* const* d_in, const int* in_sizes, int n_in,
                              void* d_out, int out_size, void* d_ws, size_t ws_size,
                              hipStream_t stream) {
    const float* P = (const float*)d_in[0];
    const float* Q = (const float*)d_in[1];
    const void* cm = d_in[2];
    const void* rm = d_in[3];
    float* out = (float*)d_out;

    k_fused<<<BATCH, TPB, 0, stream>>>(P, Q, cm, rm, out);
}

// Round 17
// 29.272 us; speedup vs baseline: 1.2268x; 1.1655x over previous
//
#include <hip/hip_runtime.h>
#include <hip/hip_fp16.h>
#include <math.h>

#define BATCH 512
#define SEQL  2048
#define NPTS  (SEQL*3)        // 6144 points per batch
#define NFLT  (NPTS*3)        // 18432 floats per batch per tensor
#define NGRP  (NPTS/4)        // 1536 groups of 4 points
#define TPB   512
#define NWAVE (TPB/64)

// ---------------- fp16 pack/unpack for the LDS stash ----------------
__device__ __forceinline__ uint2 pack4(float4 v) {
    __half2 lo = __floats2half2_rn(v.x, v.y);
    __half2 hi = __floats2half2_rn(v.z, v.w);
    uint2 r;
    r.x = *(unsigned int*)&lo;
    r.y = *(unsigned int*)&hi;
    return r;
}
__device__ __forceinline__ float4 unpack4(uint2 u) {
    __half2 lo = *(__half2*)&u.x;
    __half2 hi = *(__half2*)&u.y;
    float2 a = __half22float2(lo);
    float2 b = __half22float2(hi);
    return make_float4(a.x, a.y, b.x, b.y);
}

// ---------------- mask dtype detection (per-wave, barrier-free) ----------------
// flag: 0 = int32 {0,1}, 1 = uint8 {0,1}, 2 = float32
__device__ __forceinline__ int detect_flag_wave(const void* cm) {
    unsigned int v = ((const unsigned int*)cm)[threadIdx.x & 63];
    bool wi = __all(v <= 1u);
    bool wb = __all((v & 0xFEFEFEFEu) == 0u);
    return wi ? 0 : (wb ? 1 : 2);
}

// ---------------- reduction ----------------
template <int K>
__device__ __forceinline__ void block_reduce(float* acc, float* lds) {
#pragma unroll
    for (int k = 0; k < K; ++k) {
#pragma unroll
        for (int off = 32; off > 0; off >>= 1)
            acc[k] += __shfl_down(acc[k], off, 64);
    }
    int lane = threadIdx.x & 63;
    int wid  = threadIdx.x >> 6;
    if (lane == 0) {
#pragma unroll
        for (int k = 0; k < K; ++k) lds[wid * K + k] = acc[k];
    }
    __syncthreads();
    if (threadIdx.x == 0) {
#pragma unroll
        for (int k = 0; k < K; ++k) {
            float s = 0.f;
#pragma unroll
            for (int w = 0; w < NWAVE; ++w) s += lds[w * K + k];
            acc[k] = s;
        }
    }
}

__device__ __forceinline__ void accum_pt(float* a, float w,
                                         float px, float py, float pz,
                                         float qx, float qy, float qz) {
    a[0] += w;
    float wpx = w * px, wpy = w * py, wpz = w * pz;
    a[1] += wpx; a[2] += wpy; a[3] += wpz;
    a[4] += w * qx; a[5] += w * qy; a[6] += w * qz;
    a[7]  += wpx * qx; a[8]  += wpx * qy; a[9]  += wpx * qz;
    a[10] += wpy * qx; a[11] += wpy * qy; a[12] += wpy * qz;
    a[13] += wpz * qx; a[14] += wpz * qy; a[15] += wpz * qz;
}

// ---------------- closed-form 3x3 Kabsch, all scalars, no runtime indexing ----
// out prm: [0..8]=R, [9..11]=t (R*muP - muQ), [12]=1/d0^2, [13]=cnt
__device__ void kabsch_params(const float* s, float* o) {
    double cnt = (double)s[0];
    double cs = fmax(cnt, 1.0);
    double mup0 = (double)s[1] / cs, mup1 = (double)s[2] / cs, mup2 = (double)s[3] / cs;
    double muq0 = (double)s[4] / cs, muq1 = (double)s[5] / cs, muq2 = (double)s[6] / cs;

    double h00 = (double)s[7]  - cnt * mup0 * muq0;
    double h01 = (double)s[8]  - cnt * mup0 * muq1;
    double h02 = (double)s[9]  - cnt * mup0 * muq2;
    double h10 = (double)s[10] - cnt * mup1 * muq0;
    double h11 = (double)s[11] - cnt * mup1 * muq1;
    double h12 = (double)s[12] - cnt * mup1 * muq2;
    double h20 = (double)s[13] - cnt * mup2 * muq0;
    double h21 = (double)s[14] - cnt * mup2 * muq1;
    double h22 = (double)s[15] - cnt * mup2 * muq2;

    double a00 = h00*h00 + h10*h10 + h20*h20;
    double a01 = h00*h01 + h10*h11 + h20*h21;
    double a02 = h00*h02 + h10*h12 + h20*h22;
    double a11 = h01*h01 + h11*h11 + h21*h21;
    double a12 = h01*h02 + h11*h12 + h21*h22;
    double a22 = h02*h02 + h12*h12 + h22*h22;

    double q3  = (a00 + a11 + a22) / 3.0;
    double pp1 = a01*a01 + a02*a02 + a12*a12;
    double b00 = a00 - q3, b11 = a11 - q3, b22 = a22 - q3;
    double pp2 = b00*b00 + b11*b11 + b22*b22 + 2.0 * pp1;

    double l0, l1, l2;
    double v1x, v1y, v1z, v2x, v2y, v2z, v3x, v3y, v3z;
    if (pp2 <= 1e-24 * (q3 * q3) + 1e-290) {
        l0 = l1 = l2 = q3;
        v1x = 1; v1y = 0; v1z = 0;
        v2x = 0; v2y = 1; v2z = 0;
        v3x = 0; v3y = 0; v3z = 1;
    } else {
        double p = sqrt(pp2 / 6.0), invp = 1.0 / p;
        double c00 = b00*invp, c01 = a01*invp, c02 = a02*invp;
        double c11 = b11*invp, c12 = a12*invp, c22 = b22*invp;
        double detB = c00*(c11*c22 - c12*c12) - c01*(c01*c22 - c12*c02)
                    + c02*(c01*c12 - c11*c02);
        double r = fmin(1.0, fmax(-1.0, detB * 0.5));
        double phi = acos(r) / 3.0;
        l0 = q3 + 2.0 * p * cos(phi);
        l2 = q3 + 2.0 * p * cos(phi + 2.0943951023931953);  // +2pi/3
        l1 = 3.0 * q3 - l0 - l2;

        double aa00 = a00*a00 + a01*a01 + a02*a02;
        double aa01 = a00*a01 + a01*a11 + a02*a12;
        double aa02 = a00*a02 + a01*a12 + a02*a22;
        double aa11 = a01*a01 + a11*a11 + a12*a12;
        double aa12 = a01*a02 + a11*a12 + a12*a22;
        double aa22 = a02*a02 + a12*a12 + a22*a22;

        double s12 = l1 + l2, p12 = l1 * l2;
        double m00 = aa00 - s12*a00 + p12;
        double m01 = aa01 - s12*a01;
        double m02 = aa02 - s12*a02;
        double m11 = aa11 - s12*a11 + p12;
        double m12 = aa12 - s12*a12;
        double m22 = aa22 - s12*a22 + p12;
        double n0 = m00*m00 + m01*m01 + m02*m02;
        double n1 = m01*m01 + m11*m11 + m12*m12;
        double n2 = m02*m02 + m12*m12 + m22*m22;
        bool s0 = (n0 >= n1) && (n0 >= n2);
        bool sA = (n1 >= n2);
        v1x = s0 ? m00 : (sA ? m01 : m02);
        v1y = s0 ? m01 : (sA ? m11 : m12);
        v1z = s0 ? m02 : (sA ? m12 : m22);
        double n1v = sqrt(v1x*v1x + v1y*v1y + v1z*v1z);
        if (n1v > 1e-150) { v1x /= n1v; v1y /= n1v; v1z /= n1v; }
        else { v1x = 1; v1y = 0; v1z = 0; }

        double s01 = l0 + l1, p01 = l0 * l1;
        double t00 = aa00 - s01*a00 + p01;
        double t01 = aa01 - s01*a01;
        double t02 = aa02 - s01*a02;
        double t11 = aa11 - s01*a11 + p01;
        double t12 = aa12 - s01*a12;
        double t22 = aa22 - s01*a22 + p01;
        double u0n = t00*t00 + t01*t01 + t02*t02;
        double u1n = t01*t01 + t11*t11 + t12*t12;
        double u2n = t02*t02 + t12*t12 + t22*t22;
        bool d0c = (u0n >= u1n) && (u0n >= u2n);
        bool dA = (u1n >= u2n);
        v3x = d0c ? t00 : (dA ? t01 : t02);
        v3y = d0c ? t01 : (dA ? t11 : t12);
        v3z = d0c ? t02 : (dA ? t12 : t22);
        double dot13 = v3x*v1x + v3y*v1y + v3z*v1z;
        v3x -= dot13 * v1x; v3y -= dot13 * v1y; v3z -= dot13 * v1z;
        double n3v = sqrt(v3x*v3x + v3y*v3y + v3z*v3z);
        if (n3v > 1e-150) { v3x /= n3v; v3y /= n3v; v3z /= n3v; }
        else {
            double A0 = fabs(v1x), A1 = fabs(v1y), A2 = fabs(v1z);
            double axx = 0, axy = 0, axz = 0;
            if (A0 <= A1 && A0 <= A2) axx = 1; else if (A1 <= A2) axy = 1; else axz = 1;
            double dd = axx*v1x + axy*v1y + axz*v1z;
            v3x = axx - dd*v1x; v3y = axy - dd*v1y; v3z = axz - dd*v1z;
            double nn = sqrt(v3x*v3x + v3y*v3y + v3z*v3z);
            v3x /= nn; v3y /= nn; v3z /= nn;
        }
        v2x = v3y*v1z - v3z*v1y;
        v2y = v3z*v1x - v3x*v1z;
        v2z = v3x*v1y - v3y*v1x;
    }

    double sv0 = sqrt(fmax(l0, 0.0));
    double sv1 = sqrt(fmax(l1, 0.0));
    double sv2 = sqrt(fmax(l2, 0.0));
    double eps = sv0 * 1e-12 + 1e-300;

    double u0x, u0y, u0z, u1x, u1y, u1z, u2x, u2y, u2z;
    {
        double hx = h00*v1x + h01*v1y + h02*v1z;
        double hy = h10*v1x + h11*v1y + h12*v1z;
        double hz = h20*v1x + h21*v1y + h22*v1z;
        if (sv0 > eps) {
            double ix = hx / sv0, iy = hy / sv0, iz = hz / sv0;
            double nn = sqrt(ix*ix + iy*iy + iz*iz);
            if (nn > 1e-300) { ix /= nn; iy /= nn; iz /= nn; }
            u0x = ix; u0y = iy; u0z = iz;
        } else { u0x = 1; u0y = 0; u0z = 0; }
    }
    {
        double hx = h00*v2x + h01*v2y + h02*v2z;
        double hy = h10*v2x + h11*v2y + h12*v2z;
        double hz = h20*v2x + h21*v2y + h22*v2z;
        if (sv1 > eps) {
            double ix = hx / sv1, iy = hy / sv1, iz = hz / sv1;
            double nn = sqrt(ix*ix + iy*iy + iz*iz);
            if (nn > 1e-300) { ix /= nn; iy /= nn; iz /= nn; }
            u1x = ix; u1y = iy; u1z = iz;
        } else {
            double A0 = fabs(u0x), A1 = fabs(u0y), A2 = fabs(u0z);
            double axx = 0, axy = 0, axz = 0;
            if (A0 <= A1 && A0 <= A2) axx = 1; else if (A1 <= A2) axy = 1; else axz = 1;
            double cx = u0y*axz - u0z*axy;
            double cy = u0z*axx - u0x*axz;
            double cz = u0x*axy - u0y*axx;
            double nn = sqrt(cx*cx + cy*cy + cz*cz);
            if (nn > 1e-300) { cx /= nn; cy /= nn; cz /= nn; }
            u1x = cx; u1y = cy; u1z = cz;
        }
    }
    {
        double hx = h00*v3x + h01*v3y + h02*v3z;
        double hy = h10*v3x + h11*v3y + h12*v3z;
        double hz = h20*v3x + h21*v3y + h22*v3z;
        if (sv2 > eps) {
            double ix = hx / sv2, iy = hy / sv2, iz = hz / sv2;
            double nn = sqrt(ix*ix + iy*iy + iz*iz);
            if (nn > 1e-300) { ix /= nn; iy /= nn; iz /= nn; }
            u2x = ix; u2y = iy; u2z = iz;
        } else {
            u2x = u0y*u1z - u0z*u1y;
            u2y = u0z*u1x - u0x*u1z;
            u2z = u0x*u1y - u0y*u1x;
            double nn = sqrt(u2x*u2x + u2y*u2y + u2z*u2z);
            if (nn > 1e-300) { u2x /= nn; u2y /= nn; u2z /= nn; }
        }
    }

    double detH = h00*(h11*h22 - h12*h21) - h01*(h10*h22 - h12*h20)
                + h02*(h10*h21 - h11*h20);
    double e2 = (detH > 0.0) ? 1.0 : ((detH < 0.0) ? -1.0 : 0.0);

    double R00 = v1x*u0x + v2x*u1x + e2*v3x*u2x;
    double R01 = v1x*u0y + v2x*u1y + e2*v3x*u2y;
    double R02 = v1x*u0z + v2x*u1z + e2*v3x*u2z;
    double R10 = v1y*u0x + v2y*u1x + e2*v3y*u2x;
    double R11 = v1y*u0y + v2y*u1y + e2*v3y*u2y;
    double R12 = v1y*u0z + v2y*u1z + e2*v3y*u2z;
    double R20 = v1z*u0x + v2z*u1x + e2*v3z*u2x;
    double R21 = v1z*u0y + v2z*u1y + e2*v3z*u2y;
    double R22 = v1z*u0z + v2z*u1z + e2*v3z*u2z;

    o[0] = (float)R00; o[1] = (float)R01; o[2] = (float)R02;
    o[3] = (float)R10; o[4] = (float)R11; o[5] = (float)R12;
    o[6] = (float)R20; o[7] = (float)R21; o[8] = (float)R22;

    // t = R*muP - muQ  (phase C uses d = R*p - t - q)
    o[9]  = (float)(R00*mup0 + R01*mup1 + R02*mup2 - muq0);
    o[10] = (float)(R10*mup0 + R11*mup1 + R12*mup2 - muq1);
    o[11] = (float)(R20*mup0 + R21*mup1 + R22*mup2 - muq2);

    double n = (double)s[16];
    double d0 = 1.24 * cbrt(fmax(n - 15.0, 1e-3)) - 1.8;
    d0 = fmax(d0, 1e-3);
    o[12] = (float)(1.0 / (d0 * d0));
    o[13] = (float)cnt;
}

// ---------------- fused kernel (best measured configuration, R11) ----------
__global__ __launch_bounds__(TPB, 2) void k_fused(
    const float* __restrict__ P, const float* __restrict__ Q,
    const void* __restrict__ cmask, const void* __restrict__ rmask,
    float* __restrict__ out) {
    int b = blockIdx.x;
    int tid = threadIdx.x;
    __shared__ float lds[NWAVE * 17];
    __shared__ float prm[14];
    // fp16 stash of ALL 1536 groups: 6 x 1536 x 8B = 73.7 KB
    __shared__ uint2 sP0[NGRP], sP1[NGRP], sP2[NGRP];
    __shared__ uint2 sQ0[NGRP], sQ1[NGRP], sQ2[NGRP];
    int flag = detect_flag_wave(cmask);   // per-wave, no barrier

    const float4* Pv = (const float4*)(P + (size_t)b * NFLT);
    const float4* Qv = (const float4*)(Q + (size_t)b * NFLT);
    size_t gbase = (size_t)b * NGRP;

    // ---- phase A: loads ----
    float4 p[9], q[9];
#pragma unroll
    for (int k = 0; k < 3; ++k) {
        int g = tid + k * TPB;
        p[3*k+0] = Pv[3*g+0]; p[3*k+1] = Pv[3*g+1]; p[3*k+2] = Pv[3*g+2];
        q[3*k+0] = Qv[3*g+0]; q[3*k+1] = Qv[3*g+1]; q[3*k+2] = Qv[3*g+2];
    }
    float w[12];
    float rescnt;
    {
        size_t rg = (size_t)b * (SEQL / 4) + tid;
        if (flag == 0) {
            const int4* cm4 = (const int4*)cmask;
            int4 m0 = cm4[gbase + tid], m1 = cm4[gbase + tid + TPB], m2 = cm4[gbase + tid + 2*TPB];
            int4 rv = ((const int4*)rmask)[rg];
            w[0]=m0.x?1.f:0.f; w[1]=m0.y?1.f:0.f; w[2]=m0.z?1.f:0.f; w[3]=m0.w?1.f:0.f;
            w[4]=m1.x?1.f:0.f; w[5]=m1.y?1.f:0.f; w[6]=m1.z?1.f:0.f; w[7]=m1.w?1.f:0.f;
            w[8]=m2.x?1.f:0.f; w[9]=m2.y?1.f:0.f; w[10]=m2.z?1.f:0.f; w[11]=m2.w?1.f:0.f;
            rescnt = (rv.x?1.f:0.f) + (rv.y?1.f:0.f) + (rv.z?1.f:0.f) + (rv.w?1.f:0.f);
        } else if (flag == 1) {
            const unsigned int* cmw = (const unsigned int*)cmask;
            unsigned int m0 = cmw[gbase + tid], m1 = cmw[gbase + tid + TPB], m2 = cmw[gbase + tid + 2*TPB];
            unsigned int rv = ((const unsigned int*)rmask)[rg];
            w[0]=(m0&0xFFu)?1.f:0.f; w[1]=(m0&0xFF00u)?1.f:0.f; w[2]=(m0&0xFF0000u)?1.f:0.f; w[3]=(m0&0xFF000000u)?1.f:0.f;
            w[4]=(m1&0xFFu)?1.f:0.f; w[5]=(m1&0xFF00u)?1.f:0.f; w[6]=(m1&0xFF0000u)?1.f:0.f; w[7]=(m1&0xFF000000u)?1.f:0.f;
            w[8]=(m2&0xFFu)?1.f:0.f; w[9]=(m2&0xFF00u)?1.f:0.f; w[10]=(m2&0xFF0000u)?1.f:0.f; w[11]=(m2&0xFF000000u)?1.f:0.f;
            rescnt = (float)__popc(rv);
        } else {
            const float4* cmf = (const float4*)cmask;
            float4 m0 = cmf[gbase + tid], m1 = cmf[gbase + tid + TPB], m2 = cmf[gbase + tid + 2*TPB];
            float4 rv = ((const float4*)rmask)[rg];
            w[0]=m0.x!=0.f?1.f:0.f; w[1]=m0.y!=0.f?1.f:0.f; w[2]=m0.z!=0.f?1.f:0.f; w[3]=m0.w!=0.f?1.f:0.f;
            w[4]=m1.x!=0.f?1.f:0.f; w[5]=m1.y!=0.f?1.f:0.f; w[6]=m1.z!=0.f?1.f:0.f; w[7]=m1.w!=0.f?1.f:0.f;
            w[8]=m2.x!=0.f?1.f:0.f; w[9]=m2.y!=0.f?1.f:0.f; w[10]=m2.z!=0.f?1.f:0.f; w[11]=m2.w!=0.f?1.f:0.f;
            rescnt = (rv.x!=0.f?1.f:0.f) + (rv.y!=0.f?1.f:0.f) + (rv.z!=0.f?1.f:0.f) + (rv.w!=0.f?1.f:0.f);
        }
    }

    // stash ALL groups as fp16
#pragma unroll
    for (int k = 0; k < 3; ++k) {
        int g = tid + k * TPB;
        sP0[g] = pack4(p[3*k+0]); sP1[g] = pack4(p[3*k+1]); sP2[g] = pack4(p[3*k+2]);
        sQ0[g] = pack4(q[3*k+0]); sQ1[g] = pack4(q[3*k+1]); sQ2[g] = pack4(q[3*k+2]);
    }

    float acc[17];
#pragma unroll
    for (int k = 0; k < 17; ++k) acc[k] = 0.0f;
    acc[16] = rescnt;

#pragma unroll
    for (int k = 0; k < 3; ++k) {
        float4 p0 = p[3*k+0], p1 = p[3*k+1], p2 = p[3*k+2];
        float4 q0 = q[3*k+0], q1 = q[3*k+1], q2 = q[3*k+2];
        accum_pt(acc, w[4*k+0], p0.x, p0.y, p0.z, q0.x, q0.y, q0.z);
        accum_pt(acc, w[4*k+1], p0.w, p1.x, p1.y, q0.w, q1.x, q1.y);
        accum_pt(acc, w[4*k+2], p1.z, p1.w, p2.x, q1.z, q1.w, q2.x);
        accum_pt(acc, w[4*k+3], p2.y, p2.z, p2.w, q2.y, q2.z, q2.w);
    }

    block_reduce<17>(acc, lds);

    // ---- phase B: thread 0, scratch-free closed-form Kabsch ----
    if (tid == 0) kabsch_params(acc, prm);
    __syncthreads();

    float R0 = prm[0], R1 = prm[1], R2 = prm[2];
    float R3 = prm[3], R4 = prm[4], R5 = prm[5];
    float R6 = prm[6], R7 = prm[7], R8 = prm[8];
    float tx = prm[9], ty = prm[10], tz = prm[11];
    float inv = prm[12], cnt = prm[13];

    // ---- phase C: rotate + TM, entirely from the fp16 LDS stash ----
    float acc2 = 0.0f;
#pragma unroll
    for (int k = 0; k < 3; ++k) {
        int g = tid + k * TPB;
        float4 p0 = unpack4(sP0[g]), p1 = unpack4(sP1[g]), p2 = unpack4(sP2[g]);
        float4 q0 = unpack4(sQ0[g]), q1 = unpack4(sQ1[g]), q2 = unpack4(sQ2[g]);
        float px[4] = {p0.x, p0.w, p1.z, p2.y};
        float py[4] = {p0.y, p1.x, p1.w, p2.z};
        float pz[4] = {p0.z, p1.y, p2.x, p2.w};
        float qx[4] = {q0.x, q0.w, q1.z, q2.y};
        float qy[4] = {q0.y, q1.x, q1.w, q2.z};
        float qz[4] = {q0.z, q1.y, q2.x, q2.w};
#pragma unroll
        for (int u = 0; u < 4; ++u) {
            float dx = R0*px[u] + R1*py[u] + R2*pz[u] - tx - qx[u];
            float dy = R3*px[u] + R4*py[u] + R5*pz[u] - ty - qy[u];
            float dz = R6*px[u] + R7*py[u] + R8*pz[u] - tz - qz[u];
            float d2 = dx*dx + dy*dy + dz*dz;
            acc2 += w[4*k+u] / (1.0f + d2 * inv);
        }
    }
    __syncthreads();   // lds reuse barrier
    float a2[1] = {acc2};
    block_reduce<1>(a2, lds);
    if (tid == 0)
        out[b] = (cnt > 0.0f) ? a2[0] / fmaxf(cnt, 1.0f) : 0.0f;
}

// ---------------- launcher ----------------
extern "C" void kernel_launch(void* const* d_in, const int* in_sizes, int n_in,
                              void* d_out, int out_size, void* d_ws, size_t ws_size,
                              hipStream_t stream) {
    const float* P = (const float*)d_in[0];
    const float* Q = (const float*)d_in[1];
    const void* cm = d_in[2];
    const void* rm = d_in[3];
    float* out = (float*)d_out;

    k_fused<<<BATCH, TPB, 0, stream>>>(P, Q, cm, rm, out);
}